// Round 1
// baseline (935.613 us; speedup 1.0000x reference)
//
#include <hip/hip_runtime.h>
#include <hip/hip_bf16.h>

#define N_NODES 50000
#define N_EDGES 800000
#define DIM 64
#define NHEAD 2
#define HD 128   // NHEAD * DIM

// ---------------- init: amax=-inf, asum=0 ----------------
__global__ void k_init(float* __restrict__ amax, float* __restrict__ asum) {
    int i = blockIdx.x * blockDim.x + threadIdx.x;
    if (i < N_NODES * NHEAD) {
        amax[i] = -__builtin_inff();
        asum[i] = 0.0f;
    }
}

// ---------------- fused projections q,k,v,skip ----------------
// block = 128 threads (one per output col), NB nodes per block.
// q scaled by 1/sqrt(DIM)=0.125 here so logits kernel is a plain dot.
#define NB 8
__global__ __launch_bounds__(128) void k_proj(
    const float* __restrict__ x,
    const float* __restrict__ Wq, const float* __restrict__ bq,
    const float* __restrict__ Wk, const float* __restrict__ bk,
    const float* __restrict__ Wv, const float* __restrict__ bv,
    const float* __restrict__ Ws, const float* __restrict__ bs,
    float* __restrict__ q, float* __restrict__ k, float* __restrict__ v,
    float* __restrict__ agg)
{
    __shared__ float xs[NB][DIM];
    const int n0 = blockIdx.x * NB;
    const int t = threadIdx.x;
    for (int i = t; i < NB * DIM; i += 128) {
        int node = n0 + i / DIM;
        xs[i / DIM][i % DIM] = (node < N_NODES) ? x[node * DIM + (i % DIM)] : 0.0f;
    }
    __syncthreads();
    const int c = t;  // 0..127
    float aq[NB], ak[NB], av[NB], as_[NB];
#pragma unroll
    for (int i = 0; i < NB; i++) { aq[i] = 0.f; ak[i] = 0.f; av[i] = 0.f; as_[i] = 0.f; }
    for (int d = 0; d < DIM; d++) {
        float wq = Wq[d * HD + c];
        float wk = Wk[d * HD + c];
        float wv = Wv[d * HD + c];
        float ws = Ws[d * HD + c];
#pragma unroll
        for (int i = 0; i < NB; i++) {
            float xv = xs[i][d];
            aq[i] += xv * wq;
            ak[i] += xv * wk;
            av[i] += xv * wv;
            as_[i] += xv * ws;
        }
    }
    const float bqv = bq[c], bkv = bk[c], bvv = bv[c], bsv = bs[c];
#pragma unroll
    for (int i = 0; i < NB; i++) {
        int node = n0 + i;
        if (node < N_NODES) {
            q[(size_t)node * HD + c]   = (aq[i] + bqv) * 0.125f;
            k[(size_t)node * HD + c]   = ak[i] + bkv;
            v[(size_t)node * HD + c]   = av[i] + bvv;
            agg[(size_t)node * HD + c] = as_[i] + bsv;   // skip-connection init
        }
    }
}

// ---------------- atomic float max (monotone int/uint trick) ----------------
__device__ inline void atomicMaxF(float* addr, float val) {
    if (val >= 0.0f) atomicMax((int*)addr, __float_as_int(val));
    else             atomicMin((unsigned int*)addr, __float_as_uint(val));
}

// ---------------- edge logits + segment max ----------------
__global__ __launch_bounds__(256) void k_logits(
    const int* __restrict__ ei, const float* __restrict__ q,
    const float* __restrict__ k, float* __restrict__ alpha,
    float* __restrict__ amax)
{
    int e = blockIdx.x * blockDim.x + threadIdx.x;
    if (e >= N_EDGES) return;
    int s = ei[e];
    int d = ei[N_EDGES + e];
    const float4* qp = (const float4*)(q + (size_t)d * HD);
    const float4* kp = (const float4*)(k + (size_t)s * HD);
    float a0 = 0.f, a1 = 0.f;
#pragma unroll
    for (int i = 0; i < 16; i++) {
        float4 qv = qp[i], kv = kp[i];
        a0 += qv.x * kv.x + qv.y * kv.y + qv.z * kv.z + qv.w * kv.w;
    }
#pragma unroll
    for (int i = 16; i < 32; i++) {
        float4 qv = qp[i], kv = kp[i];
        a1 += qv.x * kv.x + qv.y * kv.y + qv.z * kv.z + qv.w * kv.w;
    }
    alpha[(size_t)e * 2 + 0] = a0;
    alpha[(size_t)e * 2 + 1] = a1;
    atomicMaxF(&amax[d * 2 + 0], a0);
    atomicMaxF(&amax[d * 2 + 1], a1);
}

// ---------------- exp(alpha - max) + segment sum ----------------
__global__ __launch_bounds__(256) void k_expsum(
    const int* __restrict__ ei, float* __restrict__ alpha,
    const float* __restrict__ amax, float* __restrict__ asum)
{
    int e = blockIdx.x * blockDim.x + threadIdx.x;
    if (e >= N_EDGES) return;
    int d = ei[N_EDGES + e];
    float m0 = amax[d * 2 + 0], m1 = amax[d * 2 + 1];
    float a0 = __expf(alpha[(size_t)e * 2 + 0] - m0);
    float a1 = __expf(alpha[(size_t)e * 2 + 1] - m1);
    alpha[(size_t)e * 2 + 0] = a0;
    alpha[(size_t)e * 2 + 1] = a1;
    atomicAdd(&asum[d * 2 + 0], a0);
    atomicAdd(&asum[d * 2 + 1], a1);
}

// ---------------- weighted scatter-aggregate of v ----------------
// 128 threads per edge (one per channel), 2 edges per 256-thread block.
__global__ __launch_bounds__(256) void k_agg(
    const int* __restrict__ ei, const float* __restrict__ alpha,
    const float* __restrict__ asum, const float* __restrict__ v,
    float* __restrict__ agg)
{
    int gid = blockIdx.x * 256 + threadIdx.x;
    int e = gid >> 7;
    int c = gid & 127;
    if (e >= N_EDGES) return;
    int s = ei[e];
    int d = ei[N_EDGES + e];
    int h = c >> 6;
    float w = alpha[(size_t)e * 2 + h] / (asum[d * 2 + h] + 1e-16f);
    atomicAdd(&agg[(size_t)d * HD + c], w * v[(size_t)s * HD + c]);
}

// ---------------- output projection 128->64 + per-node partial stats ----------------
__global__ __launch_bounds__(64) void k_conv(
    const float* __restrict__ agg, const float* __restrict__ Wc,
    const float* __restrict__ bc, float* __restrict__ out2,
    float* __restrict__ partials)
{
    int n = blockIdx.x;
    int j = threadIdx.x;  // 0..63
    const float* ag = agg + (size_t)n * HD;
    float acc = bc[j];
    for (int c = 0; c < HD; c++) acc += ag[c] * Wc[c * DIM + j];
    out2[(size_t)n * DIM + j] = acc;
    float s = acc, ss = acc * acc;
    for (int off = 32; off > 0; off >>= 1) {
        s  += __shfl_down(s, off);
        ss += __shfl_down(ss, off);
    }
    if (j == 0) { partials[n * 2 + 0] = s; partials[n * 2 + 1] = ss; }
}

// ---------------- single-block reduction of partials -> stats (f64) ----------------
__global__ __launch_bounds__(256) void k_reduce(
    const float* __restrict__ partials, double* __restrict__ stats)
{
    double s = 0.0, ss = 0.0;
    for (int i = threadIdx.x; i < N_NODES; i += 256) {
        s  += (double)partials[i * 2 + 0];
        ss += (double)partials[i * 2 + 1];
    }
    for (int off = 32; off > 0; off >>= 1) {
        s  += __shfl_down(s, off);
        ss += __shfl_down(ss, off);
    }
    __shared__ double sd[8];
    int wave = threadIdx.x >> 6;
    if ((threadIdx.x & 63) == 0) { sd[wave * 2] = s; sd[wave * 2 + 1] = ss; }
    __syncthreads();
    if (threadIdx.x == 0) {
        double S = 0.0, SS = 0.0;
        for (int w = 0; w < 4; w++) { S += sd[w * 2]; SS += sd[w * 2 + 1]; }
        stats[0] = S; stats[1] = SS;
    }
}

// ---------------- graph layernorm + gamma/beta ----------------
__global__ __launch_bounds__(256) void k_norm(
    const float* __restrict__ out2, const double* __restrict__ stats,
    const float* __restrict__ gamma, const float* __restrict__ beta,
    float* __restrict__ out)
{
    int i = blockIdx.x * blockDim.x + threadIdx.x;
    if (i >= N_NODES * DIM) return;
    const double cnt = (double)N_NODES * (double)DIM;
    double mean = stats[0] / cnt;
    double var  = stats[1] / cnt - mean * mean;
    if (var < 0.0) var = 0.0;
    float stdv = (float)sqrt(var);
    float inv  = 1.0f / (stdv + 1e-5f);
    int j = i & (DIM - 1);
    out[i] = (out2[i] - (float)mean) * inv * gamma[j] + beta[j];
}

extern "C" void kernel_launch(void* const* d_in, const int* in_sizes, int n_in,
                              void* d_out, int out_size, void* d_ws, size_t ws_size,
                              hipStream_t stream) {
    const float* x     = (const float*)d_in[0];
    const int*   ei    = (const int*)d_in[1];
    const float* Wq    = (const float*)d_in[2];
    const float* bq    = (const float*)d_in[3];
    const float* Wk    = (const float*)d_in[4];
    const float* bk    = (const float*)d_in[5];
    const float* Wv    = (const float*)d_in[6];
    const float* bv    = (const float*)d_in[7];
    const float* Wsk   = (const float*)d_in[8];
    const float* bsk   = (const float*)d_in[9];
    const float* Wc    = (const float*)d_in[10];
    const float* bc    = (const float*)d_in[11];
    const float* gamma = (const float*)d_in[12];
    const float* beta  = (const float*)d_in[13];
    float* out = (float*)d_out;

    // ws layout (float offsets)
    float* ws = (float*)d_ws;
    const size_t NF = (size_t)N_NODES * HD;          // 6.4M
    float* q     = ws;                                // [N,128]
    float* k     = ws + NF;                           // [N,128]
    float* v     = ws + 2 * NF;                       // [N,128]
    float* agg   = ws + 3 * NF;                       // [N,128]
    float* alpha = ws + 4 * NF;                       // [E,2] 1.6M
    float* amax  = alpha + (size_t)N_EDGES * 2;       // [N,2]
    float* asum  = amax + (size_t)N_NODES * 2;        // [N,2]
    float* parts = asum + (size_t)N_NODES * 2;        // [N,2]
    double* stats = (double*)(parts + (size_t)N_NODES * 2); // 2 doubles (8B aligned)
    float* out2  = q;                                 // reuse q region (dead after k_logits)

    hipLaunchKernelGGL(k_init, dim3((N_NODES * NHEAD + 255) / 256), dim3(256), 0, stream,
                       amax, asum);
    hipLaunchKernelGGL(k_proj, dim3((N_NODES + NB - 1) / NB), dim3(128), 0, stream,
                       x, Wq, bq, Wk, bk, Wv, bv, Wsk, bsk, q, k, v, agg);
    hipLaunchKernelGGL(k_logits, dim3((N_EDGES + 255) / 256), dim3(256), 0, stream,
                       ei, q, k, alpha, amax);
    hipLaunchKernelGGL(k_expsum, dim3((N_EDGES + 255) / 256), dim3(256), 0, stream,
                       ei, alpha, amax, asum);
    hipLaunchKernelGGL(k_agg, dim3((N_EDGES * 128) / 256), dim3(256), 0, stream,
                       ei, alpha, asum, v, agg);
    hipLaunchKernelGGL(k_conv, dim3(N_NODES), dim3(64), 0, stream,
                       agg, Wc, bc, out2, parts);
    hipLaunchKernelGGL(k_reduce, dim3(1), dim3(256), 0, stream, parts, stats);
    hipLaunchKernelGGL(k_norm, dim3((N_NODES * DIM + 255) / 256), dim3(256), 0, stream,
                       out2, stats, gamma, beta, out);
}

// Round 2
// 594.148 us; speedup vs baseline: 1.5747x; 1.5747x over previous
//
#include <hip/hip_runtime.h>
#include <hip/hip_bf16.h>

#define N_NODES 50000
#define N_EDGES 800000
#define DIM 64
#define NHEAD 2
#define HD 128   // NHEAD * DIM

// ---------------- zero the degree histogram ----------------
__global__ void k_zero(int* __restrict__ deg) {
    int i = blockIdx.x * blockDim.x + threadIdx.x;
    if (i < N_NODES) deg[i] = 0;
}

// ---------------- fused projections q,k,v,skip ----------------
// block = 128 threads (one per output col), NB nodes per block.
// q scaled by 1/sqrt(DIM)=0.125 here so the attention kernel does a plain dot.
#define NB 8
__global__ __launch_bounds__(128) void k_proj(
    const float* __restrict__ x,
    const float* __restrict__ Wq, const float* __restrict__ bq,
    const float* __restrict__ Wk, const float* __restrict__ bk,
    const float* __restrict__ Wv, const float* __restrict__ bv,
    const float* __restrict__ Ws, const float* __restrict__ bs,
    float* __restrict__ q, float* __restrict__ k, float* __restrict__ v,
    float* __restrict__ skip)
{
    __shared__ float xs[NB][DIM];
    const int n0 = blockIdx.x * NB;
    const int t = threadIdx.x;
    for (int i = t; i < NB * DIM; i += 128) {
        int node = n0 + i / DIM;
        xs[i / DIM][i % DIM] = (node < N_NODES) ? x[node * DIM + (i % DIM)] : 0.0f;
    }
    __syncthreads();
    const int c = t;  // 0..127
    float aq[NB], ak[NB], av[NB], as_[NB];
#pragma unroll
    for (int i = 0; i < NB; i++) { aq[i] = 0.f; ak[i] = 0.f; av[i] = 0.f; as_[i] = 0.f; }
    for (int d = 0; d < DIM; d++) {
        float wq = Wq[d * HD + c];
        float wk = Wk[d * HD + c];
        float wv = Wv[d * HD + c];
        float ws = Ws[d * HD + c];
#pragma unroll
        for (int i = 0; i < NB; i++) {
            float xv = xs[i][d];
            aq[i] += xv * wq;
            ak[i] += xv * wk;
            av[i] += xv * wv;
            as_[i] += xv * ws;
        }
    }
    const float bqv = bq[c], bkv = bk[c], bvv = bv[c], bsv = bs[c];
#pragma unroll
    for (int i = 0; i < NB; i++) {
        int node = n0 + i;
        if (node < N_NODES) {
            q[(size_t)node * HD + c]    = (aq[i] + bqv) * 0.125f;
            k[(size_t)node * HD + c]    = ak[i] + bkv;
            v[(size_t)node * HD + c]    = av[i] + bvv;
            skip[(size_t)node * HD + c] = as_[i] + bsv;
        }
    }
}

// ---------------- histogram of dst degrees ----------------
__global__ __launch_bounds__(256) void k_count(const int* __restrict__ ei, int* __restrict__ deg) {
    int e = blockIdx.x * blockDim.x + threadIdx.x;
    if (e < N_EDGES) atomicAdd(&deg[ei[N_EDGES + e]], 1);
}

// ---------------- exclusive prefix sum over 50k degrees (one block) ----------------
#define SCAN_T 1024
#define CHUNK 49   // 1024*49 = 50176 >= 50000
__global__ __launch_bounds__(SCAN_T) void k_scan(
    const int* __restrict__ deg, int* __restrict__ rowstart, int* __restrict__ cursor)
{
    __shared__ int sd[SCAN_T];
    const int t = threadIdx.x;
    const int c0 = t * CHUNK;
    int s = 0;
#pragma unroll
    for (int i = 0; i < CHUNK; i++) {
        int idx = c0 + i;
        if (idx < N_NODES) s += deg[idx];
    }
    sd[t] = s;
    __syncthreads();
    for (int off = 1; off < SCAN_T; off <<= 1) {
        int add = (t >= off) ? sd[t - off] : 0;
        __syncthreads();
        sd[t] += add;
        __syncthreads();
    }
    int run = sd[t] - s;  // exclusive prefix for this thread's chunk
#pragma unroll
    for (int i = 0; i < CHUNK; i++) {
        int idx = c0 + i;
        if (idx < N_NODES) {
            rowstart[idx] = run;
            cursor[idx] = run;
            run += deg[idx];
        }
    }
}

// ---------------- fill edge buckets: elist[pos] = src ----------------
__global__ __launch_bounds__(256) void k_fill(
    const int* __restrict__ ei, int* __restrict__ cursor, int* __restrict__ elist)
{
    int e = blockIdx.x * blockDim.x + threadIdx.x;
    if (e >= N_EDGES) return;
    int d = ei[N_EDGES + e];
    int pos = atomicAdd(&cursor[d], 1);
    elist[pos] = ei[e];  // store src id directly
}

// ---------------- fused attention: online softmax + aggregate + skip + conv + stats ----
// 4 waves / block, one wave per dst node. 50000 = 12500 * 4 (no tail).
__global__ __launch_bounds__(256) void k_attn(
    const float* __restrict__ q, const float* __restrict__ k,
    const float* __restrict__ v, const float* __restrict__ skip,
    const int* __restrict__ rowstart, const int* __restrict__ deg,
    const int* __restrict__ elist,
    const float* __restrict__ Wc, const float* __restrict__ bc,
    float* __restrict__ out2, float* __restrict__ partials)
{
    __shared__ float sh[4][HD];
    const int w = threadIdx.x >> 6;
    const int lane = threadIdx.x & 63;
    const int n = blockIdx.x * 4 + w;  // dst node
    const size_t base = (size_t)n * HD;
    const float q0 = q[base + lane], q1 = q[base + 64 + lane];
    float acc0 = 0.f, acc1 = 0.f;
    float m0 = -__builtin_inff(), m1 = -__builtin_inff();
    float l0 = 0.f, l1 = 0.f;
    const int start = rowstart[n];
    const int end = start + deg[n];
    for (int idx = start; idx < end; idx++) {
        int s = elist[idx];
        size_t sb = (size_t)s * HD;
        float k0 = k[sb + lane], k1 = k[sb + 64 + lane];
        float v0 = v[sb + lane], v1 = v[sb + 64 + lane];
        float p0 = q0 * k0, p1 = q1 * k1;
#pragma unroll
        for (int off = 32; off > 0; off >>= 1) {
            p0 += __shfl_xor(p0, off, 64);
            p1 += __shfl_xor(p1, off, 64);
        }
        // p0/p1 = full logits for head0/head1, replicated on all lanes
        float nm0 = fmaxf(m0, p0), nm1 = fmaxf(m1, p1);
        float sc0 = __expf(m0 - nm0), sc1 = __expf(m1 - nm1);
        float w0 = __expf(p0 - nm0), w1 = __expf(p1 - nm1);
        l0 = l0 * sc0 + w0;
        l1 = l1 * sc1 + w1;
        acc0 = acc0 * sc0 + w0 * v0;
        acc1 = acc1 * sc1 + w1 * v1;
        m0 = nm0; m1 = nm1;
    }
    float r0 = acc0 / (l0 + 1e-16f) + skip[base + lane];
    float r1 = acc1 / (l1 + 1e-16f) + skip[base + 64 + lane];
    sh[w][lane] = r0;
    sh[w][64 + lane] = r1;
    __syncthreads();
    // conv 128 -> 64: lane j computes output column j for node n
    float o = bc[lane];
#pragma unroll 8
    for (int c = 0; c < HD; c++) o += sh[w][c] * Wc[c * DIM + lane];
    out2[(size_t)n * DIM + lane] = o;
    float s_ = o, ss = o * o;
#pragma unroll
    for (int off = 32; off > 0; off >>= 1) {
        s_ += __shfl_xor(s_, off, 64);
        ss += __shfl_xor(ss, off, 64);
    }
    if (lane == 0) { partials[n * 2 + 0] = s_; partials[n * 2 + 1] = ss; }
}

// ---------------- single-block reduction of partials -> stats (f64) ----------------
__global__ __launch_bounds__(256) void k_reduce(
    const float* __restrict__ partials, double* __restrict__ stats)
{
    double s = 0.0, ss = 0.0;
    for (int i = threadIdx.x; i < N_NODES; i += 256) {
        s  += (double)partials[i * 2 + 0];
        ss += (double)partials[i * 2 + 1];
    }
    for (int off = 32; off > 0; off >>= 1) {
        s  += __shfl_down(s, off);
        ss += __shfl_down(ss, off);
    }
    __shared__ double sd[8];
    int wave = threadIdx.x >> 6;
    if ((threadIdx.x & 63) == 0) { sd[wave * 2] = s; sd[wave * 2 + 1] = ss; }
    __syncthreads();
    if (threadIdx.x == 0) {
        double S = 0.0, SS = 0.0;
        for (int w = 0; w < 4; w++) { S += sd[w * 2]; SS += sd[w * 2 + 1]; }
        stats[0] = S; stats[1] = SS;
    }
}

// ---------------- graph layernorm + gamma/beta (in-place on d_out) ----------------
__global__ __launch_bounds__(256) void k_norm(
    float* __restrict__ out, const double* __restrict__ stats,
    const float* __restrict__ gamma, const float* __restrict__ beta)
{
    int i = blockIdx.x * blockDim.x + threadIdx.x;
    if (i >= N_NODES * DIM) return;
    const double cnt = (double)N_NODES * (double)DIM;
    double mean = stats[0] / cnt;
    double var  = stats[1] / cnt - mean * mean;
    if (var < 0.0) var = 0.0;
    float stdv = (float)sqrt(var);
    float inv  = 1.0f / (stdv + 1e-5f);
    int j = i & (DIM - 1);
    out[i] = (out[i] - (float)mean) * inv * gamma[j] + beta[j];
}

extern "C" void kernel_launch(void* const* d_in, const int* in_sizes, int n_in,
                              void* d_out, int out_size, void* d_ws, size_t ws_size,
                              hipStream_t stream) {
    const float* x     = (const float*)d_in[0];
    const int*   ei    = (const int*)d_in[1];
    const float* Wq    = (const float*)d_in[2];
    const float* bq    = (const float*)d_in[3];
    const float* Wk    = (const float*)d_in[4];
    const float* bk    = (const float*)d_in[5];
    const float* Wv    = (const float*)d_in[6];
    const float* bv    = (const float*)d_in[7];
    const float* Wsk   = (const float*)d_in[8];
    const float* bsk   = (const float*)d_in[9];
    const float* Wc    = (const float*)d_in[10];
    const float* bc    = (const float*)d_in[11];
    const float* gamma = (const float*)d_in[12];
    const float* beta  = (const float*)d_in[13];
    float* out = (float*)d_out;

    // ws layout
    float* ws = (float*)d_ws;
    const size_t NF = (size_t)N_NODES * HD;  // 6.4M floats
    float* q    = ws;
    float* k    = ws + NF;
    float* v    = ws + 2 * NF;
    float* skip = ws + 3 * NF;
    int* deg      = (int*)(ws + 4 * NF);       // [N]
    int* rowstart = deg + N_NODES;             // [N]
    int* cursor   = rowstart + N_NODES;        // [N]
    int* elist    = cursor + N_NODES;          // [E]
    float* parts  = (float*)(elist + N_EDGES); // [N,2]
    double* stats = (double*)(parts + (size_t)N_NODES * 2);

    hipLaunchKernelGGL(k_zero, dim3((N_NODES + 255) / 256), dim3(256), 0, stream, deg);
    hipLaunchKernelGGL(k_proj, dim3((N_NODES + NB - 1) / NB), dim3(128), 0, stream,
                       x, Wq, bq, Wk, bk, Wv, bv, Wsk, bsk, q, k, v, skip);
    hipLaunchKernelGGL(k_count, dim3((N_EDGES + 255) / 256), dim3(256), 0, stream, ei, deg);
    hipLaunchKernelGGL(k_scan, dim3(1), dim3(SCAN_T), 0, stream, deg, rowstart, cursor);
    hipLaunchKernelGGL(k_fill, dim3((N_EDGES + 255) / 256), dim3(256), 0, stream,
                       ei, cursor, elist);
    hipLaunchKernelGGL(k_attn, dim3(N_NODES / 4), dim3(256), 0, stream,
                       q, k, v, skip, rowstart, deg, elist, Wc, bc, out, parts);
    hipLaunchKernelGGL(k_reduce, dim3(1), dim3(256), 0, stream, parts, stats);
    hipLaunchKernelGGL(k_norm, dim3((N_NODES * DIM + 255) / 256), dim3(256), 0, stream,
                       out, stats, gamma, beta);
}

// Round 3
// 477.232 us; speedup vs baseline: 1.9605x; 1.2450x over previous
//
#include <hip/hip_runtime.h>
#include <hip/hip_bf16.h>

#define N_NODES 50000
#define N_EDGES 800000
#define DIM 64
#define NHEAD 2
#define HD 128   // NHEAD * DIM

// ---------------- fused projections q,k,v,skip  + dst-degree histogram ----------------
// block = 128 threads (one per output col), NB=8 nodes per block.
// grid = 6250 blocks * 128 threads = 800000 == N_EDGES, so each thread also
// counts exactly one edge for the CSR histogram (deg must be pre-zeroed).
// q scaled by 1/sqrt(DIM)=0.125 here so the attention kernel does a plain dot.
#define NB 8
__global__ __launch_bounds__(128) void k_proj(
    const float* __restrict__ x, const int* __restrict__ ei,
    const float* __restrict__ Wq, const float* __restrict__ bq,
    const float* __restrict__ Wk, const float* __restrict__ bk,
    const float* __restrict__ Wv, const float* __restrict__ bv,
    const float* __restrict__ Ws, const float* __restrict__ bs,
    float* __restrict__ q, float* __restrict__ k, float* __restrict__ v,
    float* __restrict__ skip, int* __restrict__ deg)
{
    // edge-degree histogram (fused; exactly one edge per thread)
    {
        int e = blockIdx.x * 128 + threadIdx.x;   // < 800000 always
        atomicAdd(&deg[ei[N_EDGES + e]], 1);
    }
    __shared__ float xs[NB][DIM];
    const int n0 = blockIdx.x * NB;
    const int t = threadIdx.x;
    for (int i = t; i < NB * DIM; i += 128) {
        int node = n0 + i / DIM;
        xs[i / DIM][i % DIM] = (node < N_NODES) ? x[node * DIM + (i % DIM)] : 0.0f;
    }
    __syncthreads();
    const int c = t;  // 0..127
    float aq[NB], ak[NB], av[NB], as_[NB];
#pragma unroll
    for (int i = 0; i < NB; i++) { aq[i] = 0.f; ak[i] = 0.f; av[i] = 0.f; as_[i] = 0.f; }
    for (int d = 0; d < DIM; d++) {
        float wq = Wq[d * HD + c];
        float wk = Wk[d * HD + c];
        float wv = Wv[d * HD + c];
        float ws = Ws[d * HD + c];
#pragma unroll
        for (int i = 0; i < NB; i++) {
            float xv = xs[i][d];
            aq[i] += xv * wq;
            ak[i] += xv * wk;
            av[i] += xv * wv;
            as_[i] += xv * ws;
        }
    }
    const float bqv = bq[c], bkv = bk[c], bvv = bv[c], bsv = bs[c];
#pragma unroll
    for (int i = 0; i < NB; i++) {
        int node = n0 + i;
        if (node < N_NODES) {
            q[(size_t)node * HD + c]    = (aq[i] + bqv) * 0.125f;
            k[(size_t)node * HD + c]    = ak[i] + bkv;
            v[(size_t)node * HD + c]    = av[i] + bvv;
            skip[(size_t)node * HD + c] = as_[i] + bsv;
        }
    }
}

// ---------------- exclusive prefix sum over 50k degrees (one block) + zero stats ------
#define SCAN_T 1024
#define CHUNK 49   // 1024*49 = 50176 >= 50000
__global__ __launch_bounds__(SCAN_T) void k_scan(
    const int* __restrict__ deg, int* __restrict__ rowstart, int* __restrict__ cursor,
    double* __restrict__ stats)
{
    if (threadIdx.x == 0) { stats[0] = 0.0; stats[1] = 0.0; }
    __shared__ int sd[SCAN_T];
    const int t = threadIdx.x;
    const int c0 = t * CHUNK;
    int s = 0;
#pragma unroll
    for (int i = 0; i < CHUNK; i++) {
        int idx = c0 + i;
        if (idx < N_NODES) s += deg[idx];
    }
    sd[t] = s;
    __syncthreads();
    for (int off = 1; off < SCAN_T; off <<= 1) {
        int add = (t >= off) ? sd[t - off] : 0;
        __syncthreads();
        sd[t] += add;
        __syncthreads();
    }
    int run = sd[t] - s;  // exclusive prefix for this thread's chunk
#pragma unroll
    for (int i = 0; i < CHUNK; i++) {
        int idx = c0 + i;
        if (idx < N_NODES) {
            rowstart[idx] = run;
            cursor[idx] = run;
            run += deg[idx];
        }
    }
}

// ---------------- fill edge buckets: elist[pos] = src ----------------
__global__ __launch_bounds__(256) void k_fill(
    const int* __restrict__ ei, int* __restrict__ cursor, int* __restrict__ elist)
{
    int e = blockIdx.x * blockDim.x + threadIdx.x;
    if (e >= N_EDGES) return;
    int d = ei[N_EDGES + e];
    int pos = atomicAdd(&cursor[d], 1);
    elist[pos] = ei[e];  // store src id
}

// ---------------- fused attention: 4-edge-parallel online softmax + skip + conv + stats
// 4 waves / block, one wave per dst node; wave split into 4 groups of 16 lanes,
// each group handles one edge per iteration with float4 loads.
__global__ __launch_bounds__(256) void k_attn(
    const float* __restrict__ q, const float* __restrict__ k,
    const float* __restrict__ v, const float* __restrict__ skip,
    const int* __restrict__ rowstart, const int* __restrict__ deg,
    const int* __restrict__ elist,
    const float* __restrict__ Wc, const float* __restrict__ bc,
    float* __restrict__ out2, float* __restrict__ partials)
{
    __shared__ float sh[4][HD];
    const int w = threadIdx.x >> 6;
    const int lane = threadIdx.x & 63;
    const int g = lane >> 4;   // edge-group 0..3
    const int j = lane & 15;   // lane within group
    const int n = blockIdx.x * 4 + w;  // dst node
    const size_t base = (size_t)n * HD;
    const float4* qp = (const float4*)(q + base);
    const float4 q0 = qp[j];        // head0, channels 4j..4j+3
    const float4 q1 = qp[16 + j];   // head1
    float4 acc0 = {0.f, 0.f, 0.f, 0.f}, acc1 = {0.f, 0.f, 0.f, 0.f};
    float m0 = -1e30f, m1 = -1e30f, l0 = 0.f, l1 = 0.f;
    const int start = rowstart[n];
    const int end = start + deg[n];
    for (int b0 = start; b0 < end; b0 += 4) {
        int idx = b0 + g;
        bool valid = idx < end;
        int s = elist[valid ? idx : start];
        const float4* kp = (const float4*)(k + (size_t)s * HD);
        const float4* vp = (const float4*)(v + (size_t)s * HD);
        float4 k0 = kp[j], k1 = kp[16 + j];
        float4 v0 = vp[j], v1 = vp[16 + j];
        float p0 = q0.x * k0.x + q0.y * k0.y + q0.z * k0.z + q0.w * k0.w;
        float p1 = q1.x * k1.x + q1.y * k1.y + q1.z * k1.z + q1.w * k1.w;
#pragma unroll
        for (int off = 1; off < 16; off <<= 1) {
            p0 += __shfl_xor(p0, off, 64);
            p1 += __shfl_xor(p1, off, 64);
        }
        // p0/p1 = this group's edge logits (replicated in the 16 lanes)
        float nm0 = valid ? fmaxf(m0, p0) : m0;
        float nm1 = valid ? fmaxf(m1, p1) : m1;
        float sc0 = __expf(m0 - nm0), sc1 = __expf(m1 - nm1);
        float w0 = valid ? __expf(p0 - nm0) : 0.f;
        float w1 = valid ? __expf(p1 - nm1) : 0.f;
        l0 = l0 * sc0 + w0;
        l1 = l1 * sc1 + w1;
        acc0.x = acc0.x * sc0 + w0 * v0.x; acc0.y = acc0.y * sc0 + w0 * v0.y;
        acc0.z = acc0.z * sc0 + w0 * v0.z; acc0.w = acc0.w * sc0 + w0 * v0.w;
        acc1.x = acc1.x * sc1 + w1 * v1.x; acc1.y = acc1.y * sc1 + w1 * v1.y;
        acc1.z = acc1.z * sc1 + w1 * v1.z; acc1.w = acc1.w * sc1 + w1 * v1.w;
        m0 = nm0; m1 = nm1;
    }
    // merge the 4 groups' online-softmax states (butterfly over offsets 16, 32)
#pragma unroll
    for (int off = 16; off < 64; off <<= 1) {
        float om0 = __shfl_xor(m0, off, 64), om1 = __shfl_xor(m1, off, 64);
        float ol0 = __shfl_xor(l0, off, 64), ol1 = __shfl_xor(l1, off, 64);
        float4 oa0, oa1;
        oa0.x = __shfl_xor(acc0.x, off, 64); oa0.y = __shfl_xor(acc0.y, off, 64);
        oa0.z = __shfl_xor(acc0.z, off, 64); oa0.w = __shfl_xor(acc0.w, off, 64);
        oa1.x = __shfl_xor(acc1.x, off, 64); oa1.y = __shfl_xor(acc1.y, off, 64);
        oa1.z = __shfl_xor(acc1.z, off, 64); oa1.w = __shfl_xor(acc1.w, off, 64);
        float nm0 = fmaxf(m0, om0), nm1 = fmaxf(m1, om1);
        float ss0 = __expf(m0 - nm0), so0 = __expf(om0 - nm0);
        float ss1 = __expf(m1 - nm1), so1 = __expf(om1 - nm1);
        l0 = l0 * ss0 + ol0 * so0;
        l1 = l1 * ss1 + ol1 * so1;
        acc0.x = acc0.x * ss0 + oa0.x * so0; acc0.y = acc0.y * ss0 + oa0.y * so0;
        acc0.z = acc0.z * ss0 + oa0.z * so0; acc0.w = acc0.w * ss0 + oa0.w * so0;
        acc1.x = acc1.x * ss1 + oa1.x * so1; acc1.y = acc1.y * ss1 + oa1.y * so1;
        acc1.z = acc1.z * ss1 + oa1.z * so1; acc1.w = acc1.w * ss1 + oa1.w * so1;
        m0 = nm0; m1 = nm1;
    }
    if (g == 0) {
        const float4* sk = (const float4*)(skip + base);
        float4 s0 = sk[j], s1 = sk[16 + j];
        float inv0 = 1.f / (l0 + 1e-16f), inv1 = 1.f / (l1 + 1e-16f);
        float4 r0, r1;
        r0.x = acc0.x * inv0 + s0.x; r0.y = acc0.y * inv0 + s0.y;
        r0.z = acc0.z * inv0 + s0.z; r0.w = acc0.w * inv0 + s0.w;
        r1.x = acc1.x * inv1 + s1.x; r1.y = acc1.y * inv1 + s1.y;
        r1.z = acc1.z * inv1 + s1.z; r1.w = acc1.w * inv1 + s1.w;
        ((float4*)sh[w])[j] = r0;
        ((float4*)sh[w])[16 + j] = r1;
    }
    __syncthreads();
    // conv 128 -> 64: lane computes output column `lane` for node n
    float o = bc[lane];
#pragma unroll 8
    for (int c = 0; c < HD; c++) o += sh[w][c] * Wc[c * DIM + lane];
    out2[(size_t)n * DIM + lane] = o;
    float s_ = o, ss = o * o;
#pragma unroll
    for (int off = 32; off > 0; off >>= 1) {
        s_ += __shfl_xor(s_, off, 64);
        ss += __shfl_xor(ss, off, 64);
    }
    if (lane == 0) { partials[n * 2 + 0] = s_; partials[n * 2 + 1] = ss; }
}

// ---------------- multi-block reduction of partials -> stats (f64 atomics) ----------
#define RED_BLOCKS 100
__global__ __launch_bounds__(256) void k_reduce(
    const float* __restrict__ partials, double* __restrict__ stats)
{
    double s = 0.0, ss = 0.0;
    for (int i = blockIdx.x * 256 + threadIdx.x; i < N_NODES; i += RED_BLOCKS * 256) {
        s  += (double)partials[i * 2 + 0];
        ss += (double)partials[i * 2 + 1];
    }
#pragma unroll
    for (int off = 32; off > 0; off >>= 1) {
        s  += __shfl_down(s, off);
        ss += __shfl_down(ss, off);
    }
    __shared__ double sd[8];
    int wave = threadIdx.x >> 6;
    if ((threadIdx.x & 63) == 0) { sd[wave * 2] = s; sd[wave * 2 + 1] = ss; }
    __syncthreads();
    if (threadIdx.x == 0) {
        double S = 0.0, SS = 0.0;
        for (int w = 0; w < 4; w++) { S += sd[w * 2]; SS += sd[w * 2 + 1]; }
        atomicAdd(&stats[0], S);
        atomicAdd(&stats[1], SS);
    }
}

// ---------------- graph layernorm + gamma/beta (in-place on d_out) ----------------
__global__ __launch_bounds__(256) void k_norm(
    float* __restrict__ out, const double* __restrict__ stats,
    const float* __restrict__ gamma, const float* __restrict__ beta)
{
    int i = blockIdx.x * blockDim.x + threadIdx.x;
    if (i >= N_NODES * DIM) return;
    const double cnt = (double)N_NODES * (double)DIM;
    double mean = stats[0] / cnt;
    double var  = stats[1] / cnt - mean * mean;
    if (var < 0.0) var = 0.0;
    float stdv = (float)sqrt(var);
    float inv  = 1.0f / (stdv + 1e-5f);
    int j = i & (DIM - 1);
    out[i] = (out[i] - (float)mean) * inv * gamma[j] + beta[j];
}

extern "C" void kernel_launch(void* const* d_in, const int* in_sizes, int n_in,
                              void* d_out, int out_size, void* d_ws, size_t ws_size,
                              hipStream_t stream) {
    const float* x     = (const float*)d_in[0];
    const int*   ei    = (const int*)d_in[1];
    const float* Wq    = (const float*)d_in[2];
    const float* bq    = (const float*)d_in[3];
    const float* Wk    = (const float*)d_in[4];
    const float* bk    = (const float*)d_in[5];
    const float* Wv    = (const float*)d_in[6];
    const float* bv    = (const float*)d_in[7];
    const float* Wsk   = (const float*)d_in[8];
    const float* bsk   = (const float*)d_in[9];
    const float* Wc    = (const float*)d_in[10];
    const float* bc    = (const float*)d_in[11];
    const float* gamma = (const float*)d_in[12];
    const float* beta  = (const float*)d_in[13];
    float* out = (float*)d_out;

    // ws layout
    float* ws = (float*)d_ws;
    const size_t NF = (size_t)N_NODES * HD;  // 6.4M floats
    float* q    = ws;
    float* k    = ws + NF;
    float* v    = ws + 2 * NF;
    float* skip = ws + 3 * NF;
    int* deg      = (int*)(ws + 4 * NF);       // [N]
    int* rowstart = deg + N_NODES;             // [N]
    int* cursor   = rowstart + N_NODES;        // [N]
    int* elist    = cursor + N_NODES;          // [E]
    float* parts  = (float*)(elist + N_EDGES); // [N,2]
    double* stats = (double*)(parts + (size_t)N_NODES * 2);

    hipMemsetAsync(deg, 0, N_NODES * sizeof(int), stream);
    hipLaunchKernelGGL(k_proj, dim3(N_NODES / NB), dim3(128), 0, stream,
                       x, ei, Wq, bq, Wk, bk, Wv, bv, Wsk, bsk, q, k, v, skip, deg);
    hipLaunchKernelGGL(k_scan, dim3(1), dim3(SCAN_T), 0, stream, deg, rowstart, cursor, stats);
    hipLaunchKernelGGL(k_fill, dim3((N_EDGES + 255) / 256), dim3(256), 0, stream,
                       ei, cursor, elist);
    hipLaunchKernelGGL(k_attn, dim3(N_NODES / 4), dim3(256), 0, stream,
                       q, k, v, skip, rowstart, deg, elist, Wc, bc, out, parts);
    hipLaunchKernelGGL(k_reduce, dim3(RED_BLOCKS), dim3(256), 0, stream, parts, stats);
    hipLaunchKernelGGL(k_norm, dim3((N_NODES * DIM + 255) / 256), dim3(256), 0, stream,
                       out, stats, gamma, beta);
}

// Round 4
// 416.046 us; speedup vs baseline: 2.2488x; 1.1471x over previous
//
#include <hip/hip_runtime.h>
#include <hip/hip_bf16.h>

#define N_NODES 50000
#define N_EDGES 800000
#define DIM 64
#define NHEAD 2
#define HD 128   // NHEAD * DIM

__device__ __forceinline__ float bflo(unsigned u) { return __uint_as_float(u << 16); }
__device__ __forceinline__ float bfhi(unsigned u) { return __uint_as_float(u & 0xffff0000u); }

// ---------------- precompute folded weights ----------------
// Wvc[d][h*64+j] = sum_c Wv[d][h*64+c] * Wc[h*64+c][j]      (v projected through Wc per head)
// Wskipc[d][j]   = sum_c Wskip[d][c]   * Wc[c][j]
// bvc[h*64+j]    = sum_c bv[h*64+c]    * Wc[h*64+c][j]
// bskipc[j]      = bc[j] + sum_c bskip[c] * Wc[c][j]
__global__ __launch_bounds__(128) void k_prep(
    const float* __restrict__ Wv, const float* __restrict__ bv,
    const float* __restrict__ Wskip, const float* __restrict__ bskip,
    const float* __restrict__ Wc, const float* __restrict__ bc,
    float* __restrict__ Wvc, float* __restrict__ bvc,
    float* __restrict__ Wskipc, float* __restrict__ bskipc)
{
    const int d = blockIdx.x;   // 0..63
    const int t = threadIdx.x;  // 0..127
    const int h = t >> 6, j = t & 63;
    float s = 0.f;
    for (int c = 0; c < 64; c++)
        s += Wv[d * HD + h * 64 + c] * Wc[(h * 64 + c) * DIM + j];
    Wvc[d * HD + t] = s;
    if (t < 64) {
        float s2 = 0.f;
        for (int c = 0; c < HD; c++)
            s2 += Wskip[d * HD + c] * Wc[c * DIM + t];
        Wskipc[d * DIM + t] = s2;
    }
    if (d == 0) {
        float s3 = 0.f;
        for (int c = 0; c < 64; c++)
            s3 += bv[h * 64 + c] * Wc[(h * 64 + c) * DIM + j];
        bvc[t] = s3;
        if (t < 64) {
            float s4 = bc[t];
            for (int c = 0; c < HD; c++)
                s4 += bskip[c] * Wc[c * DIM + t];
            bskipc[t] = s4;
        }
    }
}

// ---------------- fused projections q, k(bf16), vc(bf16), skipc + degree histogram ----
// block = 128 threads, NB=8 nodes/block, grid = 6250 (grid*block == N_EDGES).
// q scaled by 1/sqrt(DIM)=0.125 at store.
#define NB 8
__global__ __launch_bounds__(128) void k_proj(
    const float* __restrict__ x, const int* __restrict__ ei,
    const float* __restrict__ Wq, const float* __restrict__ bq,
    const float* __restrict__ Wk, const float* __restrict__ bk,
    const float* __restrict__ Wvc, const float* __restrict__ bvc,
    const float* __restrict__ Wskipc, const float* __restrict__ bskipc,
    float* __restrict__ q, __hip_bfloat16* __restrict__ kv,
    float* __restrict__ skipc, int* __restrict__ deg)
{
    {   // fused degree histogram: exactly one edge per thread
        int e = blockIdx.x * 128 + threadIdx.x;
        atomicAdd(&deg[ei[N_EDGES + e]], 1);
    }
    __shared__ float xs[NB][DIM];
    const int n0 = blockIdx.x * NB;
    const int t = threadIdx.x;
    for (int i = t; i < NB * DIM; i += 128)
        xs[i / DIM][i % DIM] = x[(n0 + i / DIM) * DIM + (i % DIM)];
    __syncthreads();
    const int c = t;            // 0..127
    const int cs = c & 63;      // skipc column (upper half duplicates, harmless)
    float aq[NB], ak[NB], av[NB], as_[NB];
#pragma unroll
    for (int i = 0; i < NB; i++) { aq[i] = 0.f; ak[i] = 0.f; av[i] = 0.f; as_[i] = 0.f; }
    for (int d = 0; d < DIM; d++) {
        float wq = Wq[d * HD + c];
        float wk = Wk[d * HD + c];
        float wv = Wvc[d * HD + c];
        float ws = Wskipc[d * DIM + cs];
#pragma unroll
        for (int i = 0; i < NB; i++) {
            float xv = xs[i][d];
            aq[i] += xv * wq;
            ak[i] += xv * wk;
            av[i] += xv * wv;
            as_[i] += xv * ws;
        }
    }
    const float bqv = bq[c], bkv = bk[c], bvv = bvc[c], bsv = bskipc[cs];
#pragma unroll
    for (int i = 0; i < NB; i++) {
        int node = n0 + i;
        q[(size_t)node * HD + c] = (aq[i] + bqv) * 0.125f;
        kv[(size_t)node * 256 + c]       = __float2bfloat16(ak[i] + bkv);
        kv[(size_t)node * 256 + 128 + c] = __float2bfloat16(av[i] + bvv);
        if (c < 64) skipc[(size_t)node * DIM + c] = as_[i] + bsv;
    }
}

// ---------------- exclusive prefix sum over degrees (one block) + zero stats ---------
#define SCAN_T 1024
#define CHUNK 49   // 1024*49 >= 50000
__global__ __launch_bounds__(SCAN_T) void k_scan(
    const int* __restrict__ deg, int* __restrict__ rowstart, int* __restrict__ cursor,
    double* __restrict__ stats)
{
    if (threadIdx.x == 0) { stats[0] = 0.0; stats[1] = 0.0; }
    __shared__ int sd[SCAN_T];
    const int t = threadIdx.x;
    const int c0 = t * CHUNK;
    int s = 0;
#pragma unroll
    for (int i = 0; i < CHUNK; i++) {
        int idx = c0 + i;
        if (idx < N_NODES) s += deg[idx];
    }
    sd[t] = s;
    __syncthreads();
    for (int off = 1; off < SCAN_T; off <<= 1) {
        int add = (t >= off) ? sd[t - off] : 0;
        __syncthreads();
        sd[t] += add;
        __syncthreads();
    }
    int run = sd[t] - s;
#pragma unroll
    for (int i = 0; i < CHUNK; i++) {
        int idx = c0 + i;
        if (idx < N_NODES) {
            rowstart[idx] = run;
            cursor[idx] = run;
            run += deg[idx];
        }
    }
}

// ---------------- fill edge buckets: elist[pos] = src ----------------
__global__ __launch_bounds__(256) void k_fill(
    const int* __restrict__ ei, int* __restrict__ cursor, int* __restrict__ elist)
{
    int e = blockIdx.x * blockDim.x + threadIdx.x;
    if (e >= N_EDGES) return;
    int d = ei[N_EDGES + e];
    int pos = atomicAdd(&cursor[d], 1);
    elist[pos] = ei[e];
}

// ---------------- fused attention: 8-edge-parallel softmax-aggregate + skipc + stats --
// 4 waves/block, one wave per dst node; 8 groups x 8 lanes, one edge per group/iter.
// kv row (512B): [k head0 (64 bf16) | k head1 | vc head0 | vc head1].
// No max-subtraction: logits are O(1) (q pre-scaled), exp cannot overflow.
__global__ __launch_bounds__(256) void k_attn(
    const float* __restrict__ q, const __hip_bfloat16* __restrict__ kv,
    const float* __restrict__ skipc,
    const int* __restrict__ rowstart, const int* __restrict__ deg,
    const int* __restrict__ elist,
    float* __restrict__ out2, float* __restrict__ partials)
{
    const int w = threadIdx.x >> 6;
    const int lane = threadIdx.x & 63;
    const int g = lane >> 3;   // edge group 0..7
    const int j = lane & 7;    // lane in group; covers channels 8j..8j+7
    const int n = blockIdx.x * 4 + w;
    const float4* qp = (const float4*)(q + (size_t)n * HD);
    const float4 qa = qp[2 * j],      qb = qp[2 * j + 1];      // head0
    const float4 qc = qp[16 + 2 * j], qd = qp[17 + 2 * j];     // head1
    float acc0[8], acc1[8];
#pragma unroll
    for (int i = 0; i < 8; i++) { acc0[i] = 0.f; acc1[i] = 0.f; }
    float l0 = 0.f, l1 = 0.f;
    const int start = rowstart[n];
    const int end = start + deg[n];
    for (int b0 = start; b0 < end; b0 += 8) {
        int idx = b0 + g;
        bool valid = idx < end;
        int s = elist[valid ? idx : start];
        const uint4* kp = (const uint4*)(kv + (size_t)s * 256);
        uint4 K0 = kp[j], K1 = kp[8 + j];
        uint4 V0 = kp[16 + j], V1 = kp[24 + j];
        float p0 = qa.x * bflo(K0.x) + qa.y * bfhi(K0.x)
                 + qa.z * bflo(K0.y) + qa.w * bfhi(K0.y)
                 + qb.x * bflo(K0.z) + qb.y * bfhi(K0.z)
                 + qb.z * bflo(K0.w) + qb.w * bfhi(K0.w);
        float p1 = qc.x * bflo(K1.x) + qc.y * bfhi(K1.x)
                 + qc.z * bflo(K1.y) + qc.w * bfhi(K1.y)
                 + qd.x * bflo(K1.z) + qd.y * bfhi(K1.z)
                 + qd.z * bflo(K1.w) + qd.w * bfhi(K1.w);
#pragma unroll
        for (int off = 1; off < 8; off <<= 1) {
            p0 += __shfl_xor(p0, off, 64);
            p1 += __shfl_xor(p1, off, 64);
        }
        float w0 = valid ? __expf(p0) : 0.f;
        float w1 = valid ? __expf(p1) : 0.f;
        l0 += w0; l1 += w1;
        acc0[0] += w0 * bflo(V0.x); acc0[1] += w0 * bfhi(V0.x);
        acc0[2] += w0 * bflo(V0.y); acc0[3] += w0 * bfhi(V0.y);
        acc0[4] += w0 * bflo(V0.z); acc0[5] += w0 * bfhi(V0.z);
        acc0[6] += w0 * bflo(V0.w); acc0[7] += w0 * bfhi(V0.w);
        acc1[0] += w1 * bflo(V1.x); acc1[1] += w1 * bfhi(V1.x);
        acc1[2] += w1 * bflo(V1.y); acc1[3] += w1 * bfhi(V1.y);
        acc1[4] += w1 * bflo(V1.z); acc1[5] += w1 * bfhi(V1.z);
        acc1[6] += w1 * bflo(V1.w); acc1[7] += w1 * bfhi(V1.w);
    }
    // merge the 8 groups (plain sums — no max bookkeeping)
#pragma unroll
    for (int off = 8; off < 64; off <<= 1) {
        l0 += __shfl_xor(l0, off, 64);
        l1 += __shfl_xor(l1, off, 64);
#pragma unroll
        for (int i = 0; i < 8; i++) {
            acc0[i] += __shfl_xor(acc0[i], off, 64);
            acc1[i] += __shfl_xor(acc1[i], off, 64);
        }
    }
    if (g == 0) {
        float inv0 = 1.f / (l0 + 1e-16f), inv1 = 1.f / (l1 + 1e-16f);
        const float4* sk = (const float4*)(skipc + (size_t)n * DIM);
        float4 sa = sk[2 * j], sb = sk[2 * j + 1];
        float o[8];
        o[0] = acc0[0] * inv0 + acc1[0] * inv1 + sa.x;
        o[1] = acc0[1] * inv0 + acc1[1] * inv1 + sa.y;
        o[2] = acc0[2] * inv0 + acc1[2] * inv1 + sa.z;
        o[3] = acc0[3] * inv0 + acc1[3] * inv1 + sa.w;
        o[4] = acc0[4] * inv0 + acc1[4] * inv1 + sb.x;
        o[5] = acc0[5] * inv0 + acc1[5] * inv1 + sb.y;
        o[6] = acc0[6] * inv0 + acc1[6] * inv1 + sb.z;
        o[7] = acc0[7] * inv0 + acc1[7] * inv1 + sb.w;
        float4 r0 = {o[0], o[1], o[2], o[3]}, r1 = {o[4], o[5], o[6], o[7]};
        float4* op = (float4*)(out2 + (size_t)n * DIM);
        op[2 * j] = r0; op[2 * j + 1] = r1;
        float s_ = 0.f, ss = 0.f;
#pragma unroll
        for (int i = 0; i < 8; i++) { s_ += o[i]; ss += o[i] * o[i]; }
#pragma unroll
        for (int off = 1; off < 8; off <<= 1) {
            s_ += __shfl_xor(s_, off, 64);
            ss += __shfl_xor(ss, off, 64);
        }
        if (j == 0) { partials[n * 2 + 0] = s_; partials[n * 2 + 1] = ss; }
    }
}

// ---------------- multi-block reduction of partials -> stats (f64 atomics) ----------
#define RED_BLOCKS 100
__global__ __launch_bounds__(256) void k_reduce(
    const float* __restrict__ partials, double* __restrict__ stats)
{
    double s = 0.0, ss = 0.0;
    for (int i = blockIdx.x * 256 + threadIdx.x; i < N_NODES; i += RED_BLOCKS * 256) {
        s  += (double)partials[i * 2 + 0];
        ss += (double)partials[i * 2 + 1];
    }
#pragma unroll
    for (int off = 32; off > 0; off >>= 1) {
        s  += __shfl_down(s, off);
        ss += __shfl_down(ss, off);
    }
    __shared__ double sd[8];
    int wave = threadIdx.x >> 6;
    if ((threadIdx.x & 63) == 0) { sd[wave * 2] = s; sd[wave * 2 + 1] = ss; }
    __syncthreads();
    if (threadIdx.x == 0) {
        double S = 0.0, SS = 0.0;
        for (int w = 0; w < 4; w++) { S += sd[w * 2]; SS += sd[w * 2 + 1]; }
        atomicAdd(&stats[0], S);
        atomicAdd(&stats[1], SS);
    }
}

// ---------------- graph layernorm + gamma/beta (in-place on d_out) ----------------
__global__ __launch_bounds__(256) void k_norm(
    float* __restrict__ out, const double* __restrict__ stats,
    const float* __restrict__ gamma, const float* __restrict__ beta)
{
    int i = blockIdx.x * blockDim.x + threadIdx.x;
    if (i >= N_NODES * DIM) return;
    const double cnt = (double)N_NODES * (double)DIM;
    double mean = stats[0] / cnt;
    double var  = stats[1] / cnt - mean * mean;
    if (var < 0.0) var = 0.0;
    float stdv = (float)sqrt(var);
    float inv  = 1.0f / (stdv + 1e-5f);
    int j = i & (DIM - 1);
    out[i] = (out[i] - (float)mean) * inv * gamma[j] + beta[j];
}

extern "C" void kernel_launch(void* const* d_in, const int* in_sizes, int n_in,
                              void* d_out, int out_size, void* d_ws, size_t ws_size,
                              hipStream_t stream) {
    const float* x     = (const float*)d_in[0];
    const int*   ei    = (const int*)d_in[1];
    const float* Wq    = (const float*)d_in[2];
    const float* bq    = (const float*)d_in[3];
    const float* Wk    = (const float*)d_in[4];
    const float* bk    = (const float*)d_in[5];
    const float* Wv    = (const float*)d_in[6];
    const float* bv    = (const float*)d_in[7];
    const float* Wsk   = (const float*)d_in[8];
    const float* bsk   = (const float*)d_in[9];
    const float* Wc    = (const float*)d_in[10];
    const float* bc    = (const float*)d_in[11];
    const float* gamma = (const float*)d_in[12];
    const float* beta  = (const float*)d_in[13];
    float* out = (float*)d_out;

    // ws layout
    float* ws = (float*)d_ws;
    const size_t NF = (size_t)N_NODES * HD;   // 6.4M floats
    float* q = ws;                                        // [N,128] f32
    __hip_bfloat16* kv = (__hip_bfloat16*)(ws + NF);      // [N,256] bf16 (k|vc)
    float* skipc = ws + 2 * NF;                           // [N,64]  f32
    float* Wvc    = skipc + (size_t)N_NODES * DIM;        // [64,128]
    float* bvc    = Wvc + 64 * HD;                        // [128]
    float* Wskipc = bvc + HD;                             // [64,64]
    float* bskipc = Wskipc + 64 * DIM;                    // [64]
    int* deg      = (int*)(bskipc + DIM);                 // [N]
    int* rowstart = deg + N_NODES;                        // [N]
    int* cursor   = rowstart + N_NODES;                   // [N]
    int* elist    = cursor + N_NODES;                     // [E]
    float* parts  = (float*)(elist + N_EDGES);            // [N,2]
    double* stats = (double*)(parts + (size_t)N_NODES * 2);

    hipMemsetAsync(deg, 0, N_NODES * sizeof(int), stream);
    hipLaunchKernelGGL(k_prep, dim3(64), dim3(128), 0, stream,
                       Wv, bv, Wsk, bsk, Wc, bc, Wvc, bvc, Wskipc, bskipc);
    hipLaunchKernelGGL(k_proj, dim3(N_NODES / NB), dim3(128), 0, stream,
                       x, ei, Wq, bq, Wk, bk, Wvc, bvc, Wskipc, bskipc,
                       q, kv, skipc, deg);
    hipLaunchKernelGGL(k_scan, dim3(1), dim3(SCAN_T), 0, stream, deg, rowstart, cursor, stats);
    hipLaunchKernelGGL(k_fill, dim3((N_EDGES + 255) / 256), dim3(256), 0, stream,
                       ei, cursor, elist);
    hipLaunchKernelGGL(k_attn, dim3(N_NODES / 4), dim3(256), 0, stream,
                       q, kv, skipc, rowstart, deg, elist, out, parts);
    hipLaunchKernelGGL(k_reduce, dim3(RED_BLOCKS), dim3(256), 0, stream, parts, stats);
    hipLaunchKernelGGL(k_norm, dim3((N_NODES * DIM + 255) / 256), dim3(256), 0, stream,
                       out, stats, gamma, beta);
}

// Round 5
// 308.722 us; speedup vs baseline: 3.0306x; 1.3476x over previous
//
#include <hip/hip_runtime.h>
#include <hip/hip_bf16.h>

#define N_NODES 50000
#define N_EDGES 800000
#define DIM 64
#define NHEAD 2
#define HD 128   // NHEAD * DIM

#define SCAN_B 196   // ceil(50000/256)

__device__ __forceinline__ float bflo(unsigned u) { return __uint_as_float(u << 16); }
__device__ __forceinline__ float bfhi(unsigned u) { return __uint_as_float(u & 0xffff0000u); }

// ---------------- precompute folded weights ----------------
// Wvc[d][h*64+j] = sum_c Wv[d][h*64+c] * Wc[h*64+c][j]
// Wskipc[d][j]   = sum_c Wskip[d][c]   * Wc[c][j]
// bvc[h*64+j]    = sum_c bv[h*64+c]    * Wc[h*64+c][j]
// bskipc[j]      = bc[j] + sum_c bskip[c] * Wc[c][j]
__global__ __launch_bounds__(128) void k_prep(
    const float* __restrict__ Wv, const float* __restrict__ bv,
    const float* __restrict__ Wskip, const float* __restrict__ bskip,
    const float* __restrict__ Wc, const float* __restrict__ bc,
    float* __restrict__ Wvc, float* __restrict__ bvc,
    float* __restrict__ Wskipc, float* __restrict__ bskipc)
{
    const int d = blockIdx.x;   // 0..63
    const int t = threadIdx.x;  // 0..127
    const int h = t >> 6, j = t & 63;
    float s = 0.f;
    for (int c = 0; c < 64; c++)
        s += Wv[d * HD + h * 64 + c] * Wc[(h * 64 + c) * DIM + j];
    Wvc[d * HD + t] = s;
    if (t < 64) {
        float s2 = 0.f;
        for (int c = 0; c < HD; c++)
            s2 += Wskip[d * HD + c] * Wc[c * DIM + t];
        Wskipc[d * DIM + t] = s2;
    }
    if (d == 0) {
        float s3 = 0.f;
        for (int c = 0; c < 64; c++)
            s3 += bv[h * 64 + c] * Wc[(h * 64 + c) * DIM + j];
        bvc[t] = s3;
        if (t < 64) {
            float s4 = bc[t];
            for (int c = 0; c < HD; c++)
                s4 += bskip[c] * Wc[c * DIM + t];
            bskipc[t] = s4;
        }
    }
}

// ---------------- fused projections q, k(bf16), vc(bf16), skipc + degree histogram ----
#define NB 8
__global__ __launch_bounds__(128) void k_proj(
    const float* __restrict__ x, const int* __restrict__ ei,
    const float* __restrict__ Wq, const float* __restrict__ bq,
    const float* __restrict__ Wk, const float* __restrict__ bk,
    const float* __restrict__ Wvc, const float* __restrict__ bvc,
    const float* __restrict__ Wskipc, const float* __restrict__ bskipc,
    float* __restrict__ q, __hip_bfloat16* __restrict__ kv,
    float* __restrict__ skipc, int* __restrict__ deg)
{
    {   // fused degree histogram: exactly one edge per thread (grid*block == N_EDGES)
        int e = blockIdx.x * 128 + threadIdx.x;
        atomicAdd(&deg[ei[N_EDGES + e]], 1);
    }
    __shared__ float xs[NB][DIM];
    const int n0 = blockIdx.x * NB;
    const int t = threadIdx.x;
    for (int i = t; i < NB * DIM; i += 128)
        xs[i / DIM][i % DIM] = x[(n0 + i / DIM) * DIM + (i % DIM)];
    __syncthreads();
    const int c = t;            // 0..127
    const int cs = c & 63;
    float aq[NB], ak[NB], av[NB], as_[NB];
#pragma unroll
    for (int i = 0; i < NB; i++) { aq[i] = 0.f; ak[i] = 0.f; av[i] = 0.f; as_[i] = 0.f; }
    for (int d = 0; d < DIM; d++) {
        float wq = Wq[d * HD + c];
        float wk = Wk[d * HD + c];
        float wv = Wvc[d * HD + c];
        float ws = Wskipc[d * DIM + cs];
#pragma unroll
        for (int i = 0; i < NB; i++) {
            float xv = xs[i][d];
            aq[i] += xv * wq;
            ak[i] += xv * wk;
            av[i] += xv * wv;
            as_[i] += xv * ws;
        }
    }
    const float bqv = bq[c], bkv = bk[c], bvv = bvc[c], bsv = bskipc[cs];
#pragma unroll
    for (int i = 0; i < NB; i++) {
        int node = n0 + i;
        q[(size_t)node * HD + c] = (aq[i] + bqv) * 0.125f;
        kv[(size_t)node * 256 + c]       = __float2bfloat16(ak[i] + bkv);
        kv[(size_t)node * 256 + 128 + c] = __float2bfloat16(av[i] + bvv);
        if (c < 64) skipc[(size_t)node * DIM + c] = as_[i] + bsv;
    }
}

// ---------------- scan phase A: per-block degree sums (+ zero stats) ----------------
__global__ __launch_bounds__(256) void k_scanA(
    const int* __restrict__ deg, int* __restrict__ bsum, double* __restrict__ stats)
{
    if (blockIdx.x == 0 && threadIdx.x == 0) { stats[0] = 0.0; stats[1] = 0.0; }
    int idx = blockIdx.x * 256 + threadIdx.x;
    int d = (idx < N_NODES) ? deg[idx] : 0;
    int s = d;
#pragma unroll
    for (int off = 32; off > 0; off >>= 1) s += __shfl_down(s, off);
    __shared__ int sd[4];
    if ((threadIdx.x & 63) == 0) sd[threadIdx.x >> 6] = s;
    __syncthreads();
    if (threadIdx.x == 0) bsum[blockIdx.x] = sd[0] + sd[1] + sd[2] + sd[3];
}

// ---------------- scan phase B: block offset + local exclusive scan ----------------
__global__ __launch_bounds__(256) void k_scanB(
    const int* __restrict__ deg, const int* __restrict__ bsum,
    int* __restrict__ rowstart, int* __restrict__ cursor)
{
    const int t = threadIdx.x;
    const int b = blockIdx.x;
    // block offset = sum of bsum[0..b)
    int v = (t < b) ? bsum[t] : 0;   // b <= 195 < 256, single pass covers all
#pragma unroll
    for (int off = 32; off > 0; off >>= 1) v += __shfl_down(v, off);
    __shared__ int swv[4];
    if ((t & 63) == 0) swv[t >> 6] = v;
    __shared__ int sd[256];
    int idx = b * 256 + t;
    int d = (idx < N_NODES) ? deg[idx] : 0;
    sd[t] = d;
    __syncthreads();
    int base = swv[0] + swv[1] + swv[2] + swv[3];
    // Hillis-Steele inclusive scan over 256 entries
    for (int off = 1; off < 256; off <<= 1) {
        int add = (t >= off) ? sd[t - off] : 0;
        __syncthreads();
        sd[t] += add;
        __syncthreads();
    }
    if (idx < N_NODES) {
        int excl = base + sd[t] - d;
        rowstart[idx] = excl;
        cursor[idx] = excl;
    }
}

// ---------------- fill edge buckets: elist[pos] = src ----------------
__global__ __launch_bounds__(256) void k_fill(
    const int* __restrict__ ei, int* __restrict__ cursor, int* __restrict__ elist)
{
    int e = blockIdx.x * blockDim.x + threadIdx.x;
    if (e >= N_EDGES) return;
    int d = ei[N_EDGES + e];
    int pos = atomicAdd(&cursor[d], 1);
    elist[pos] = ei[e];
}

// ---------------- fused attention: 8-edge-parallel softmax-aggregate + skipc + stats --
// 4 waves/block, one wave per dst node; 8 groups x 8 lanes, one edge per group/iter.
// kv row (512B): [k head0 | k head1 | vc head0 | vc head1], bf16.
// No max-subtraction: q pre-scaled, logits O(1), exp cannot overflow.
__global__ __launch_bounds__(256) void k_attn(
    const float* __restrict__ q, const __hip_bfloat16* __restrict__ kv,
    const float* __restrict__ skipc,
    const int* __restrict__ rowstart, const int* __restrict__ deg,
    const int* __restrict__ elist,
    float* __restrict__ out2, float* __restrict__ partials)
{
    const int w = threadIdx.x >> 6;
    const int lane = threadIdx.x & 63;
    const int g = lane >> 3;   // edge group 0..7
    const int j = lane & 7;    // channels 8j..8j+7
    const int n = blockIdx.x * 4 + w;
    const float4* qp = (const float4*)(q + (size_t)n * HD);
    const float4 qa = qp[2 * j],      qb = qp[2 * j + 1];      // head0
    const float4 qc = qp[16 + 2 * j], qd = qp[17 + 2 * j];     // head1
    float acc0[8], acc1[8];
#pragma unroll
    for (int i = 0; i < 8; i++) { acc0[i] = 0.f; acc1[i] = 0.f; }
    float l0 = 0.f, l1 = 0.f;
    const int start = rowstart[n];
    const int end = start + deg[n];
    for (int b0 = start; b0 < end; b0 += 8) {
        int idx = b0 + g;
        bool valid = idx < end;
        int s = elist[valid ? idx : start];
        const uint4* kp = (const uint4*)(kv + (size_t)s * 256);
        uint4 K0 = kp[j], K1 = kp[8 + j];
        uint4 V0 = kp[16 + j], V1 = kp[24 + j];
        float p0 = qa.x * bflo(K0.x) + qa.y * bfhi(K0.x)
                 + qa.z * bflo(K0.y) + qa.w * bfhi(K0.y)
                 + qb.x * bflo(K0.z) + qb.y * bfhi(K0.z)
                 + qb.z * bflo(K0.w) + qb.w * bfhi(K0.w);
        float p1 = qc.x * bflo(K1.x) + qc.y * bfhi(K1.x)
                 + qc.z * bflo(K1.y) + qc.w * bfhi(K1.y)
                 + qd.x * bflo(K1.z) + qd.y * bfhi(K1.z)
                 + qd.z * bflo(K1.w) + qd.w * bfhi(K1.w);
#pragma unroll
        for (int off = 1; off < 8; off <<= 1) {
            p0 += __shfl_xor(p0, off, 64);
            p1 += __shfl_xor(p1, off, 64);
        }
        float w0 = valid ? __expf(p0) : 0.f;
        float w1 = valid ? __expf(p1) : 0.f;
        l0 += w0; l1 += w1;
        acc0[0] += w0 * bflo(V0.x); acc0[1] += w0 * bfhi(V0.x);
        acc0[2] += w0 * bflo(V0.y); acc0[3] += w0 * bfhi(V0.y);
        acc0[4] += w0 * bflo(V0.z); acc0[5] += w0 * bfhi(V0.z);
        acc0[6] += w0 * bflo(V0.w); acc0[7] += w0 * bfhi(V0.w);
        acc1[0] += w1 * bflo(V1.x); acc1[1] += w1 * bfhi(V1.x);
        acc1[2] += w1 * bflo(V1.y); acc1[3] += w1 * bfhi(V1.y);
        acc1[4] += w1 * bflo(V1.z); acc1[5] += w1 * bfhi(V1.z);
        acc1[6] += w1 * bflo(V1.w); acc1[7] += w1 * bfhi(V1.w);
    }
#pragma unroll
    for (int off = 8; off < 64; off <<= 1) {
        l0 += __shfl_xor(l0, off, 64);
        l1 += __shfl_xor(l1, off, 64);
#pragma unroll
        for (int i = 0; i < 8; i++) {
            acc0[i] += __shfl_xor(acc0[i], off, 64);
            acc1[i] += __shfl_xor(acc1[i], off, 64);
        }
    }
    if (g == 0) {
        float inv0 = 1.f / (l0 + 1e-16f), inv1 = 1.f / (l1 + 1e-16f);
        const float4* sk = (const float4*)(skipc + (size_t)n * DIM);
        float4 sa = sk[2 * j], sb = sk[2 * j + 1];
        float o[8];
        o[0] = acc0[0] * inv0 + acc1[0] * inv1 + sa.x;
        o[1] = acc0[1] * inv0 + acc1[1] * inv1 + sa.y;
        o[2] = acc0[2] * inv0 + acc1[2] * inv1 + sa.z;
        o[3] = acc0[3] * inv0 + acc1[3] * inv1 + sa.w;
        o[4] = acc0[4] * inv0 + acc1[4] * inv1 + sb.x;
        o[5] = acc0[5] * inv0 + acc1[5] * inv1 + sb.y;
        o[6] = acc0[6] * inv0 + acc1[6] * inv1 + sb.z;
        o[7] = acc0[7] * inv0 + acc1[7] * inv1 + sb.w;
        float4 r0 = {o[0], o[1], o[2], o[3]}, r1 = {o[4], o[5], o[6], o[7]};
        float4* op = (float4*)(out2 + (size_t)n * DIM);
        op[2 * j] = r0; op[2 * j + 1] = r1;
        float s_ = 0.f, ss = 0.f;
#pragma unroll
        for (int i = 0; i < 8; i++) { s_ += o[i]; ss += o[i] * o[i]; }
#pragma unroll
        for (int off = 1; off < 8; off <<= 1) {
            s_ += __shfl_xor(s_, off, 64);
            ss += __shfl_xor(ss, off, 64);
        }
        if (j == 0) { partials[n * 2 + 0] = s_; partials[n * 2 + 1] = ss; }
    }
}

// ---------------- multi-block reduction of partials -> stats (f64 atomics) ----------
#define RED_BLOCKS 100
__global__ __launch_bounds__(256) void k_reduce(
    const float* __restrict__ partials, double* __restrict__ stats)
{
    double s = 0.0, ss = 0.0;
    for (int i = blockIdx.x * 256 + threadIdx.x; i < N_NODES; i += RED_BLOCKS * 256) {
        s  += (double)partials[i * 2 + 0];
        ss += (double)partials[i * 2 + 1];
    }
#pragma unroll
    for (int off = 32; off > 0; off >>= 1) {
        s  += __shfl_down(s, off);
        ss += __shfl_down(ss, off);
    }
    __shared__ double sd[8];
    int wave = threadIdx.x >> 6;
    if ((threadIdx.x & 63) == 0) { sd[wave * 2] = s; sd[wave * 2 + 1] = ss; }
    __syncthreads();
    if (threadIdx.x == 0) {
        double S = 0.0, SS = 0.0;
        for (int w = 0; w < 4; w++) { S += sd[w * 2]; SS += sd[w * 2 + 1]; }
        atomicAdd(&stats[0], S);
        atomicAdd(&stats[1], SS);
    }
}

// ---------------- graph layernorm + gamma/beta (in-place on d_out) ----------------
__global__ __launch_bounds__(256) void k_norm(
    float* __restrict__ out, const double* __restrict__ stats,
    const float* __restrict__ gamma, const float* __restrict__ beta)
{
    int i = blockIdx.x * blockDim.x + threadIdx.x;
    if (i >= N_NODES * DIM) return;
    const double cnt = (double)N_NODES * (double)DIM;
    double mean = stats[0] / cnt;
    double var  = stats[1] / cnt - mean * mean;
    if (var < 0.0) var = 0.0;
    float stdv = (float)sqrt(var);
    float inv  = 1.0f / (stdv + 1e-5f);
    int j = i & (DIM - 1);
    out[i] = (out[i] - (float)mean) * inv * gamma[j] + beta[j];
}

extern "C" void kernel_launch(void* const* d_in, const int* in_sizes, int n_in,
                              void* d_out, int out_size, void* d_ws, size_t ws_size,
                              hipStream_t stream) {
    const float* x     = (const float*)d_in[0];
    const int*   ei    = (const int*)d_in[1];
    const float* Wq    = (const float*)d_in[2];
    const float* bq    = (const float*)d_in[3];
    const float* Wk    = (const float*)d_in[4];
    const float* bk    = (const float*)d_in[5];
    const float* Wv    = (const float*)d_in[6];
    const float* bv    = (const float*)d_in[7];
    const float* Wsk   = (const float*)d_in[8];
    const float* bsk   = (const float*)d_in[9];
    const float* Wc    = (const float*)d_in[10];
    const float* bc    = (const float*)d_in[11];
    const float* gamma = (const float*)d_in[12];
    const float* beta  = (const float*)d_in[13];
    float* out = (float*)d_out;

    // ws layout
    float* ws = (float*)d_ws;
    const size_t NF = (size_t)N_NODES * HD;   // 6.4M floats
    float* q = ws;                                        // [N,128] f32
    __hip_bfloat16* kv = (__hip_bfloat16*)(ws + NF);      // [N,256] bf16 (k|vc)
    float* skipc = ws + 2 * NF;                           // [N,64]  f32
    float* Wvc    = skipc + (size_t)N_NODES * DIM;        // [64,128]
    float* bvc    = Wvc + 64 * HD;                        // [128]
    float* Wskipc = bvc + HD;                             // [64,64]
    float* bskipc = Wskipc + 64 * DIM;                    // [64]
    int* deg      = (int*)(bskipc + DIM);                 // [N]
    int* rowstart = deg + N_NODES;                        // [N]
    int* cursor   = rowstart + N_NODES;                   // [N]
    int* bsum     = cursor + N_NODES;                     // [SCAN_B]
    int* elist    = bsum + 256;                           // [E]
    float* parts  = (float*)(elist + N_EDGES);            // [N,2]
    double* stats = (double*)(parts + (size_t)N_NODES * 2);

    hipMemsetAsync(deg, 0, N_NODES * sizeof(int), stream);
    hipLaunchKernelGGL(k_prep, dim3(64), dim3(128), 0, stream,
                       Wv, bv, Wsk, bsk, Wc, bc, Wvc, bvc, Wskipc, bskipc);
    hipLaunchKernelGGL(k_proj, dim3(N_NODES / NB), dim3(128), 0, stream,
                       x, ei, Wq, bq, Wk, bk, Wvc, bvc, Wskipc, bskipc,
                       q, kv, skipc, deg);
    hipLaunchKernelGGL(k_scanA, dim3(SCAN_B), dim3(256), 0, stream, deg, bsum, stats);
    hipLaunchKernelGGL(k_scanB, dim3(SCAN_B), dim3(256), 0, stream,
                       deg, bsum, rowstart, cursor);
    hipLaunchKernelGGL(k_fill, dim3((N_EDGES + 255) / 256), dim3(256), 0, stream,
                       ei, cursor, elist);
    hipLaunchKernelGGL(k_attn, dim3(N_NODES / 4), dim3(256), 0, stream,
                       q, kv, skipc, rowstart, deg, elist, out, parts);
    hipLaunchKernelGGL(k_reduce, dim3(RED_BLOCKS), dim3(256), 0, stream, parts, stats);
    hipLaunchKernelGGL(k_norm, dim3((N_NODES * DIM + 255) / 256), dim3(256), 0, stream,
                       out, stats, gamma, beta);
}

// Round 6
// 286.202 us; speedup vs baseline: 3.2691x; 1.0787x over previous
//
#include <hip/hip_runtime.h>
#include <hip/hip_bf16.h>

#define N_NODES 50000
#define N_EDGES 800000
#define DIM 64
#define NHEAD 2
#define HD 128     // NHEAD * DIM
#define NCOL 448   // 128 q + 128 k + 128 vc + 64 skipc
#define NPAD 50048 // xb rows padded to multiple of 64

#define SCAN_B 196   // ceil(50000/256)

typedef short bf16x8 __attribute__((ext_vector_type(8)));
typedef float f32x16 __attribute__((ext_vector_type(16)));

__device__ __forceinline__ float bflo(unsigned u) { return __uint_as_float(u << 16); }
__device__ __forceinline__ float bfhi(unsigned u) { return __uint_as_float(u & 0xffff0000u); }
__device__ __forceinline__ unsigned short f2bf(float f) {
    unsigned u = __float_as_uint(f);
    unsigned r = (u + 0x7fffu + ((u >> 16) & 1u)) >> 16;   // RNE
    return (unsigned short)r;
}

// ---------------- build combined transposed weight WallT[448][64] bf16 + ball[448] ----
// cols 0..127   : 0.125*Wq   (bias 0.125*bq)
// cols 128..255 : Wk         (bias bk)
// cols 256..383 : Wvc = per-head Wv@Wc   (bias bv@Wc)
// cols 384..447 : Wskipc = Wskip@Wc      (bias bc + bskip@Wc)
__global__ __launch_bounds__(64) void k_prep(
    const float* __restrict__ Wq, const float* __restrict__ bq,
    const float* __restrict__ Wk, const float* __restrict__ bk,
    const float* __restrict__ Wv, const float* __restrict__ bv,
    const float* __restrict__ Wskip, const float* __restrict__ bskip,
    const float* __restrict__ Wc, const float* __restrict__ bc,
    unsigned short* __restrict__ WallT, float* __restrict__ ball)
{
    const int j = blockIdx.x;    // output column 0..447
    const int d = threadIdx.x;   // k index 0..63
    float w, b;
    if (j < 128) {
        w = Wq[d * HD + j] * 0.125f;
        b = bq[j] * 0.125f;
    } else if (j < 256) {
        int jj = j - 128;
        w = Wk[d * HD + jj];
        b = bk[jj];
    } else if (j < 384) {
        int jj = j - 256;
        int h = jj >> 6, jc = jj & 63;
        float s = 0.f, sb = 0.f;
        for (int c = 0; c < 64; c++) {
            float wc = Wc[(h * 64 + c) * DIM + jc];
            s  += Wv[d * HD + h * 64 + c] * wc;
            sb += bv[h * 64 + c] * wc;
        }
        w = s; b = sb;
    } else {
        int jj = j - 384;
        float s = 0.f, sb = bc[jj];
        for (int c = 0; c < HD; c++) {
            float wc = Wc[c * DIM + jj];
            s  += Wskip[d * HD + c] * wc;
            sb += bskip[c] * wc;
        }
        w = s; b = sb;
    }
    WallT[j * 64 + d] = f2bf(w);
    if (d == 0) ball[j] = b;
}

// ---------------- cast x -> bf16 + degree histogram ----------------
// grid*block == 800000 == N_EDGES; each thread casts 4 x-elements and counts 1 edge.
__global__ __launch_bounds__(256) void k_cast(
    const float* __restrict__ x, const int* __restrict__ ei,
    unsigned short* __restrict__ xb, int* __restrict__ deg)
{
    int gid = blockIdx.x * 256 + threadIdx.x;
    atomicAdd(&deg[ei[N_EDGES + gid]], 1);
    float4 xv = ((const float4*)x)[gid];
    ushort4 o;
    o.x = f2bf(xv.x); o.y = f2bf(xv.y); o.z = f2bf(xv.z); o.w = f2bf(xv.w);
    ((ushort4*)xb)[gid] = o;
}

// ---------------- MFMA projection GEMM: [50048 x 64] @ [64 x 448] ----------------
// 4 waves/block; wave w: row-tile rt=w>>1 (32 nodes), col-tiles ct0..ct0+6 (w&1 ? 7..13 : 0..6).
// A frag: xb[node][k], lane m=lane&31, k=(lane>>5)*8+j -> contiguous 16B load.
// B frag: WallT[col][k], lane n=lane&31, same k pattern -> contiguous 16B load.
// C/D: col=lane&31, row=(reg&3)+8*(reg>>2)+4*(lane>>5)  [m74/m101 verified]
__global__ __launch_bounds__(256) void k_proj_mfma(
    const unsigned short* __restrict__ xb, const unsigned short* __restrict__ WallT,
    const float* __restrict__ ball,
    float* __restrict__ q, unsigned short* __restrict__ kv, float* __restrict__ skipc)
{
    const int w = threadIdx.x >> 6;
    const int lane = threadIdx.x & 63;
    const int col = lane & 31;
    const int khalf = lane >> 5;
    const int n0 = blockIdx.x * 64 + (w >> 1) * 32;
    const int ct0 = (w & 1) * 7;
    const int rowbase = 4 * khalf;

    bf16x8 afrag[4];
    const unsigned short* ap = xb + (size_t)(n0 + col) * 64 + khalf * 8;
#pragma unroll
    for (int kk = 0; kk < 4; kk++)
        afrag[kk] = *((const bf16x8*)(ap + kk * 16));

    for (int t = 0; t < 7; t++) {
        const int ct = ct0 + t;
        const int gc = ct * 32 + col;
        const float b = ball[gc];
        f32x16 acc;
#pragma unroll
        for (int r = 0; r < 16; r++) acc[r] = b;
        const unsigned short* bp = WallT + (size_t)gc * 64 + khalf * 8;
#pragma unroll
        for (int kk = 0; kk < 4; kk++) {
            bf16x8 bfrag = *((const bf16x8*)(bp + kk * 16));
            acc = __builtin_amdgcn_mfma_f32_32x32x16_bf16(afrag[kk], bfrag, acc, 0, 0, 0);
        }
        if (gc < 128) {
#pragma unroll
            for (int r = 0; r < 16; r++) {
                int node = n0 + (r & 3) + 8 * (r >> 2) + rowbase;
                if (node < N_NODES) q[(size_t)node * HD + gc] = acc[r];
            }
        } else if (gc < 256) {
#pragma unroll
            for (int r = 0; r < 16; r++) {
                int node = n0 + (r & 3) + 8 * (r >> 2) + rowbase;
                if (node < N_NODES) kv[(size_t)node * 256 + (gc - 128)] = f2bf(acc[r]);
            }
        } else if (gc < 384) {
#pragma unroll
            for (int r = 0; r < 16; r++) {
                int node = n0 + (r & 3) + 8 * (r >> 2) + rowbase;
                if (node < N_NODES) kv[(size_t)node * 256 + 128 + (gc - 256)] = f2bf(acc[r]);
            }
        } else {
#pragma unroll
            for (int r = 0; r < 16; r++) {
                int node = n0 + (r & 3) + 8 * (r >> 2) + rowbase;
                if (node < N_NODES) skipc[(size_t)node * DIM + (gc - 384)] = acc[r];
            }
        }
    }
}

// ---------------- scan phase A: per-block degree sums (+ zero stats) ----------------
__global__ __launch_bounds__(256) void k_scanA(
    const int* __restrict__ deg, int* __restrict__ bsum, double* __restrict__ stats)
{
    if (blockIdx.x == 0 && threadIdx.x == 0) { stats[0] = 0.0; stats[1] = 0.0; }
    int idx = blockIdx.x * 256 + threadIdx.x;
    int d = (idx < N_NODES) ? deg[idx] : 0;
    int s = d;
#pragma unroll
    for (int off = 32; off > 0; off >>= 1) s += __shfl_down(s, off);
    __shared__ int sd[4];
    if ((threadIdx.x & 63) == 0) sd[threadIdx.x >> 6] = s;
    __syncthreads();
    if (threadIdx.x == 0) bsum[blockIdx.x] = sd[0] + sd[1] + sd[2] + sd[3];
}

// ---------------- scan phase B: block offset + local exclusive scan ----------------
__global__ __launch_bounds__(256) void k_scanB(
    const int* __restrict__ deg, const int* __restrict__ bsum,
    int* __restrict__ rowstart, int* __restrict__ cursor)
{
    const int t = threadIdx.x;
    const int b = blockIdx.x;
    int v = (t < b) ? bsum[t] : 0;   // b <= 195 < 256
#pragma unroll
    for (int off = 32; off > 0; off >>= 1) v += __shfl_down(v, off);
    __shared__ int swv[4];
    if ((t & 63) == 0) swv[t >> 6] = v;
    __shared__ int sd[256];
    int idx = b * 256 + t;
    int d = (idx < N_NODES) ? deg[idx] : 0;
    sd[t] = d;
    __syncthreads();
    int base = swv[0] + swv[1] + swv[2] + swv[3];
    for (int off = 1; off < 256; off <<= 1) {
        int add = (t >= off) ? sd[t - off] : 0;
        __syncthreads();
        sd[t] += add;
        __syncthreads();
    }
    if (idx < N_NODES) {
        int excl = base + sd[t] - d;
        rowstart[idx] = excl;
        cursor[idx] = excl;
    }
}

// ---------------- fill edge buckets: elist[pos] = src ----------------
__global__ __launch_bounds__(256) void k_fill(
    const int* __restrict__ ei, int* __restrict__ cursor, int* __restrict__ elist)
{
    int e = blockIdx.x * blockDim.x + threadIdx.x;
    if (e >= N_EDGES) return;
    int d = ei[N_EDGES + e];
    int pos = atomicAdd(&cursor[d], 1);
    elist[pos] = ei[e];
}

// ---------------- fused attention: 8-edge-parallel softmax-aggregate + skipc + stats --
// 4 waves/block, one wave per dst node; 8 groups x 8 lanes, one edge per group/iter.
// kv row (512B): [k h0 | k h1 | vc h0 | vc h1], bf16. q pre-scaled -> no max-subtract.
__global__ __launch_bounds__(256) void k_attn(
    const float* __restrict__ q, const unsigned short* __restrict__ kv,
    const float* __restrict__ skipc,
    const int* __restrict__ rowstart, const int* __restrict__ deg,
    const int* __restrict__ elist,
    float* __restrict__ out2, float* __restrict__ partials)
{
    const int w = threadIdx.x >> 6;
    const int lane = threadIdx.x & 63;
    const int g = lane >> 3;   // edge group 0..7
    const int j = lane & 7;    // channels 8j..8j+7
    const int n = blockIdx.x * 4 + w;
    const float4* qp = (const float4*)(q + (size_t)n * HD);
    const float4 qa = qp[2 * j],      qb = qp[2 * j + 1];      // head0
    const float4 qc = qp[16 + 2 * j], qd = qp[17 + 2 * j];     // head1
    float acc0[8], acc1[8];
#pragma unroll
    for (int i = 0; i < 8; i++) { acc0[i] = 0.f; acc1[i] = 0.f; }
    float l0 = 0.f, l1 = 0.f;
    const int start = rowstart[n];
    const int end = start + deg[n];
    for (int b0 = start; b0 < end; b0 += 8) {
        int idx = b0 + g;
        bool valid = idx < end;
        int s = elist[valid ? idx : start];
        const uint4* kp = (const uint4*)(kv + (size_t)s * 256);
        uint4 K0 = kp[j], K1 = kp[8 + j];
        uint4 V0 = kp[16 + j], V1 = kp[24 + j];
        float p0 = qa.x * bflo(K0.x) + qa.y * bfhi(K0.x)
                 + qa.z * bflo(K0.y) + qa.w * bfhi(K0.y)
                 + qb.x * bflo(K0.z) + qb.y * bfhi(K0.z)
                 + qb.z * bflo(K0.w) + qb.w * bfhi(K0.w);
        float p1 = qc.x * bflo(K1.x) + qc.y * bfhi(K1.x)
                 + qc.z * bflo(K1.y) + qc.w * bfhi(K1.y)
                 + qd.x * bflo(K1.z) + qd.y * bfhi(K1.z)
                 + qd.z * bflo(K1.w) + qd.w * bfhi(K1.w);
#pragma unroll
        for (int off = 1; off < 8; off <<= 1) {
            p0 += __shfl_xor(p0, off, 64);
            p1 += __shfl_xor(p1, off, 64);
        }
        float w0 = valid ? __expf(p0) : 0.f;
        float w1 = valid ? __expf(p1) : 0.f;
        l0 += w0; l1 += w1;
        acc0[0] += w0 * bflo(V0.x); acc0[1] += w0 * bfhi(V0.x);
        acc0[2] += w0 * bflo(V0.y); acc0[3] += w0 * bfhi(V0.y);
        acc0[4] += w0 * bflo(V0.z); acc0[5] += w0 * bfhi(V0.z);
        acc0[6] += w0 * bflo(V0.w); acc0[7] += w0 * bfhi(V0.w);
        acc1[0] += w1 * bflo(V1.x); acc1[1] += w1 * bfhi(V1.x);
        acc1[2] += w1 * bflo(V1.y); acc1[3] += w1 * bfhi(V1.y);
        acc1[4] += w1 * bflo(V1.z); acc1[5] += w1 * bfhi(V1.z);
        acc1[6] += w1 * bflo(V1.w); acc1[7] += w1 * bfhi(V1.w);
    }
#pragma unroll
    for (int off = 8; off < 64; off <<= 1) {
        l0 += __shfl_xor(l0, off, 64);
        l1 += __shfl_xor(l1, off, 64);
#pragma unroll
        for (int i = 0; i < 8; i++) {
            acc0[i] += __shfl_xor(acc0[i], off, 64);
            acc1[i] += __shfl_xor(acc1[i], off, 64);
        }
    }
    if (g == 0) {
        float inv0 = 1.f / (l0 + 1e-16f), inv1 = 1.f / (l1 + 1e-16f);
        const float4* sk = (const float4*)(skipc + (size_t)n * DIM);
        float4 sa = sk[2 * j], sb = sk[2 * j + 1];
        float o[8];
        o[0] = acc0[0] * inv0 + acc1[0] * inv1 + sa.x;
        o[1] = acc0[1] * inv0 + acc1[1] * inv1 + sa.y;
        o[2] = acc0[2] * inv0 + acc1[2] * inv1 + sa.z;
        o[3] = acc0[3] * inv0 + acc1[3] * inv1 + sa.w;
        o[4] = acc0[4] * inv0 + acc1[4] * inv1 + sb.x;
        o[5] = acc0[5] * inv0 + acc1[5] * inv1 + sb.y;
        o[6] = acc0[6] * inv0 + acc1[6] * inv1 + sb.z;
        o[7] = acc0[7] * inv0 + acc1[7] * inv1 + sb.w;
        float4 r0 = {o[0], o[1], o[2], o[3]}, r1 = {o[4], o[5], o[6], o[7]};
        float4* op = (float4*)(out2 + (size_t)n * DIM);
        op[2 * j] = r0; op[2 * j + 1] = r1;
        float s_ = 0.f, ss = 0.f;
#pragma unroll
        for (int i = 0; i < 8; i++) { s_ += o[i]; ss += o[i] * o[i]; }
#pragma unroll
        for (int off = 1; off < 8; off <<= 1) {
            s_ += __shfl_xor(s_, off, 64);
            ss += __shfl_xor(ss, off, 64);
        }
        if (j == 0) { partials[n * 2 + 0] = s_; partials[n * 2 + 1] = ss; }
    }
}

// ---------------- multi-block reduction of partials -> stats (f64 atomics) ----------
#define RED_BLOCKS 100
__global__ __launch_bounds__(256) void k_reduce(
    const float* __restrict__ partials, double* __restrict__ stats)
{
    double s = 0.0, ss = 0.0;
    for (int i = blockIdx.x * 256 + threadIdx.x; i < N_NODES; i += RED_BLOCKS * 256) {
        s  += (double)partials[i * 2 + 0];
        ss += (double)partials[i * 2 + 1];
    }
#pragma unroll
    for (int off = 32; off > 0; off >>= 1) {
        s  += __shfl_down(s, off);
        ss += __shfl_down(ss, off);
    }
    __shared__ double sd[8];
    int wave = threadIdx.x >> 6;
    if ((threadIdx.x & 63) == 0) { sd[wave * 2] = s; sd[wave * 2 + 1] = ss; }
    __syncthreads();
    if (threadIdx.x == 0) {
        double S = 0.0, SS = 0.0;
        for (int w = 0; w < 4; w++) { S += sd[w * 2]; SS += sd[w * 2 + 1]; }
        atomicAdd(&stats[0], S);
        atomicAdd(&stats[1], SS);
    }
}

// ---------------- graph layernorm + gamma/beta (in-place on d_out) ----------------
__global__ __launch_bounds__(256) void k_norm(
    float* __restrict__ out, const double* __restrict__ stats,
    const float* __restrict__ gamma, const float* __restrict__ beta)
{
    int i = blockIdx.x * blockDim.x + threadIdx.x;
    if (i >= N_NODES * DIM) return;
    const double cnt = (double)N_NODES * (double)DIM;
    double mean = stats[0] / cnt;
    double var  = stats[1] / cnt - mean * mean;
    if (var < 0.0) var = 0.0;
    float stdv = (float)sqrt(var);
    float inv  = 1.0f / (stdv + 1e-5f);
    int j = i & (DIM - 1);
    out[i] = (out[i] - (float)mean) * inv * gamma[j] + beta[j];
}

extern "C" void kernel_launch(void* const* d_in, const int* in_sizes, int n_in,
                              void* d_out, int out_size, void* d_ws, size_t ws_size,
                              hipStream_t stream) {
    const float* x     = (const float*)d_in[0];
    const int*   ei    = (const int*)d_in[1];
    const float* Wq    = (const float*)d_in[2];
    const float* bq    = (const float*)d_in[3];
    const float* Wk    = (const float*)d_in[4];
    const float* bk    = (const float*)d_in[5];
    const float* Wv    = (const float*)d_in[6];
    const float* bv    = (const float*)d_in[7];
    const float* Wsk   = (const float*)d_in[8];
    const float* bsk   = (const float*)d_in[9];
    const float* Wc    = (const float*)d_in[10];
    const float* bc    = (const float*)d_in[11];
    const float* gamma = (const float*)d_in[12];
    const float* beta  = (const float*)d_in[13];
    float* out = (float*)d_out;

    // ws layout
    float* ws = (float*)d_ws;
    const size_t NF = (size_t)N_NODES * HD;               // 6.4M floats
    float* q = ws;                                        // [N,128] f32
    unsigned short* kv = (unsigned short*)(ws + NF);      // [N,256] bf16 (k|vc)
    float* skipc = ws + 2 * NF;                           // [N,64]  f32
    unsigned short* xb = (unsigned short*)(skipc + (size_t)N_NODES * DIM); // [NPAD,64] bf16
    unsigned short* WallT = xb + (size_t)NPAD * 64;       // [448,64] bf16
    float* ball   = (float*)(WallT + NCOL * 64);          // [448]
    int* deg      = (int*)(ball + NCOL);                  // [N]
    int* rowstart = deg + N_NODES;                        // [N]
    int* cursor   = rowstart + N_NODES;                   // [N]
    int* bsum     = cursor + N_NODES;                     // [256]
    int* elist    = bsum + 256;                           // [E]
    float* parts  = (float*)(elist + N_EDGES);            // [N,2]
    double* stats = (double*)(parts + (size_t)N_NODES * 2);

    hipMemsetAsync(deg, 0, N_NODES * sizeof(int), stream);
    hipLaunchKernelGGL(k_prep, dim3(NCOL), dim3(64), 0, stream,
                       Wq, bq, Wk, bk, Wv, bv, Wsk, bsk, Wc, bc, WallT, ball);
    hipLaunchKernelGGL(k_cast, dim3(N_EDGES / 256), dim3(256), 0, stream,
                       x, ei, xb, deg);
    hipLaunchKernelGGL(k_proj_mfma, dim3(NPAD / 64), dim3(256), 0, stream,
                       xb, WallT, ball, q, kv, skipc);
    hipLaunchKernelGGL(k_scanA, dim3(SCAN_B), dim3(256), 0, stream, deg, bsum, stats);
    hipLaunchKernelGGL(k_scanB, dim3(SCAN_B), dim3(256), 0, stream,
                       deg, bsum, rowstart, cursor);
    hipLaunchKernelGGL(k_fill, dim3((N_EDGES + 255) / 256), dim3(256), 0, stream,
                       ei, cursor, elist);
    hipLaunchKernelGGL(k_attn, dim3(N_NODES / 4), dim3(256), 0, stream,
                       q, kv, skipc, rowstart, deg, elist, out, parts);
    hipLaunchKernelGGL(k_reduce, dim3(RED_BLOCKS), dim3(256), 0, stream, parts, stats);
    hipLaunchKernelGGL(k_norm, dim3((N_NODES * DIM + 255) / 256), dim3(256), 0, stream,
                       out, stats, gamma, beta);
}